// Round 14
// baseline (786.924 us; speedup 1.0000x reference)
//
#include <hip/hip_runtime.h>
#include <hip/hip_bf16.h>
#include <hip/hip_cooperative_groups.h>
#include <math.h>
#include <string.h>

namespace cg = cooperative_groups;

#define B 32
#define CIN 22
#define T 5000
#define EMB 64
#define P 100
#define HOP 25
#define OC 40
#define FC 120
#define NBIN 11
#define NFR 200

#define TCH 256
#define CROWS 304     // TCH + 24 halo each side
#define RSTRIDE 40    // ushorts per xs row

#define XPAD 5128
#define TWROW 24
#define GRID 512

typedef __attribute__((ext_vector_type(8))) short bf16x8;
typedef __attribute__((ext_vector_type(4))) float f32x4;

__device__ __forceinline__ unsigned short f2bf(float f) {
  unsigned u = __float_as_uint(f);
  unsigned r = (u + 0x7FFFu + ((u >> 16) & 1u)) >> 16;
  return (unsigned short)r;
}
__device__ __forceinline__ float bf2f(unsigned short u) {
  return __uint_as_float(((unsigned)u) << 16);
}
__device__ __forceinline__ float fast_elu(float y) {
  return y > 0.f ? y : (__builtin_amdgcn_exp2f(y * 1.44269504088896340736f) - 1.0f);
}
__device__ __forceinline__ unsigned pack2bf(float a, float b) {
  __hip_bfloat162 h = __float22bfloat162_rn(make_float2(a, b));
  unsigned u;
  memcpy(&u, &h, 4);
  return u;
}
__device__ __forceinline__ float wave_sum_f(float v) {
  #pragma unroll
  for (int off = 1; off < 64; off <<= 1) v += __shfl_xor(v, off);
  return v;
}
__device__ __forceinline__ int wave_sum_i(int v) {
  #pragma unroll
  for (int off = 1; off < 64; off <<= 1) v += __shfl_xor(v, off);
  return v;
}

struct MegaArgs {
  const float* w1[3]; const float* b1[3]; const float* w2[3]; const float* b2[3];
  const float* g[3];  const float* bt[3]; const float* m[3];  const float* v[3];
  const float* x;
  unsigned short* pw;
  float* A; float* Bc; float* tw; float* comb;
  const float* aw1; const float* ab1;
  const float* ag;  const float* abt;
  const float* am;  const float* av;
  const float* aw2; const float* ab2;
  const float* proj_w; const float* proj_b;
  unsigned short* feats;
  float* out_grid; float* out_acti; float* out_emb;
  int* ends_i; int* grid_i;
};

struct Smem {
  union {
    unsigned short xs[CROWS * RSTRIDE];   // conv: 24320 B (max)
    float xsh[XPAD];                      // stft: 20512 B
    struct {
      float cl[CIN * NFR];
      float actL[NFR];
      float aiL[P];
      float fL[P];
      int giL[P];
      int sI[P];
      float red;
    } a;
    struct {
      float s[16 * FC];
      float m[16 * FC];
      float pooled[FC];
    } p;
  };
};

// ---------------- Phase 1 unit: weight pack / twiddles / affine ----------------
__device__ void phase1_unit(const MegaArgs& args, int u, int tid) {
  if (u < 498) {
    int id = u * 256 + tid;
    int s, KS, fbase, idl;
    if (id < 13824)       { s = 0; KS = 9;  fbase = 0;   idl = id; }
    else if (id < 52224)  { s = 1; KS = 25; fbase = 27;  idl = id - 13824; }
    else                  { s = 2; KS = 49; fbase = 102; idl = id - 52224; }
    int fi = idl >> 9, rem = idl & 511;
    int lane = rem >> 3, j = rem & 7;
    int k = fi / 3, ot = fi - k * 3;
    int m = lane & 15, h = ((lane >> 4) << 3) + j;
    int o = ot * 16 + m;
    float val = 0.f;
    if (h < CIN && o < OC) {
      const float* w1 = args.w1[s];
      const float* w2 = args.w2[s];
      for (int i = 0; i < OC; ++i)
        val = fmaf(w2[(o * OC + i) * CIN + h], w1[i * KS + k], val);
    }
    args.pw[(size_t)(fbase + fi) * 512 + rem] = f2bf(val);
  } else if (u < 504) {
    int id = (u - 498) * 256 + tid;
    if (id < 1408) {
      int n = id & 127, k = id >> 7;
      const double PI = 3.14159265358979323846;
      double ang = -2.0 * PI * (double)((k + 5) * n) / 128.0;
      double win = 0.5 * (1.0 - cos(2.0 * PI * (double)n / 128.0));
      args.tw[n * TWROW + 2 * k]     = (float)(cos(ang) * win);
      args.tw[n * TWROW + 2 * k + 1] = (float)(sin(ang) * win);
    } else if (id < 1536) {
      int n = id - 1408;
      args.tw[n * TWROW + 22] = 0.f;
      args.tw[n * TWROW + 23] = 0.f;
    }
  } else {
    if (tid < 120) {
      int s = tid / 40, o = tid - s * 40;
      const float* w2 = args.w2[s];
      float sc = args.g[s][o] / sqrtf(args.v[s][o] + 1e-5f);
      float cc = args.b2[s][o];
      for (int i = 0; i < OC; ++i) {
        float sh = 0.f;
        for (int h = 0; h < CIN; ++h) sh += w2[(o * OC + i) * CIN + h];
        cc = fmaf(args.b1[s][i], sh, cc);
      }
      args.A[tid] = sc;
      args.Bc[tid] = cc * sc + (args.bt[s][o] - args.m[s][o] * sc);
    }
  }
}

// ---------------- Phase 2 unit: STFT power -> comb ----------------
__device__ void phase2_unit(const MegaArgs& args, int bc, int tid, float* xsh) {
  const float* xr = args.x + (size_t)bc * T;
  for (int i = tid; i < XPAD; i += 256) {
    int mm = i - 64;
    mm = (mm < 0) ? -mm : mm;
    mm = (mm >= T) ? (2 * T - 2 - mm) : mm;
    xsh[i] = xr[mm];
  }
  __syncthreads();
  int fr = tid;
  if (fr < NFR) {
    float cr[NBIN], ci[NBIN];
    #pragma unroll
    for (int k = 0; k < NBIN; ++k) { cr[k] = 0.f; ci[k] = 0.f; }
    const float* xw = xsh + fr * HOP;
    #pragma unroll 2
    for (int n = 0; n < 128; ++n) {
      float xv = xw[n];
      const float4* t4 = reinterpret_cast<const float4*>(args.tw + n * TWROW);
      float4 w0 = t4[0], w1 = t4[1], w2 = t4[2], w3 = t4[3], w4 = t4[4], w5 = t4[5];
      cr[0] = fmaf(xv, w0.x, cr[0]); ci[0] = fmaf(xv, w0.y, ci[0]);
      cr[1] = fmaf(xv, w0.z, cr[1]); ci[1] = fmaf(xv, w0.w, ci[1]);
      cr[2] = fmaf(xv, w1.x, cr[2]); ci[2] = fmaf(xv, w1.y, ci[2]);
      cr[3] = fmaf(xv, w1.z, cr[3]); ci[3] = fmaf(xv, w1.w, ci[3]);
      cr[4] = fmaf(xv, w2.x, cr[4]); ci[4] = fmaf(xv, w2.y, ci[4]);
      cr[5] = fmaf(xv, w2.z, cr[5]); ci[5] = fmaf(xv, w2.w, ci[5]);
      cr[6] = fmaf(xv, w3.x, cr[6]); ci[6] = fmaf(xv, w3.y, ci[6]);
      cr[7] = fmaf(xv, w3.z, cr[7]); ci[7] = fmaf(xv, w3.w, ci[7]);
      cr[8] = fmaf(xv, w4.x, cr[8]); ci[8] = fmaf(xv, w4.y, ci[8]);
      cr[9] = fmaf(xv, w4.z, cr[9]); ci[9] = fmaf(xv, w4.w, ci[9]);
      cr[10] = fmaf(xv, w5.x, cr[10]); ci[10] = fmaf(xv, w5.y, ci[10]);
    }
    float p[NBIN];
    #pragma unroll
    for (int k = 0; k < NBIN; ++k) p[k] = cr[k] * cr[k] + ci[k] * ci[k];
    float beta = 0.f;
    #pragma unroll
    for (int k = 2; k < NBIN; ++k) beta += p[k];
    args.comb[bc * NFR + fr] = 0.5f * (p[0] + p[1]) + beta * (1.f / 9.f);
  }
  __syncthreads();
}

// ---------------- Phase 3 pieces ----------------
template <int KS, int FB, int SBASE>
__device__ __forceinline__ void scale_body(const unsigned short* __restrict__ xs,
                                           const unsigned short* __restrict__ pw,
                                           const float* __restrict__ Aff,
                                           const float* __restrict__ Bff,
                                           unsigned short* __restrict__ feats,
                                           int b, int t0, int wt0, int lane) {
  constexpr int PAD = (KS - 1) / 2;
  const int n = lane & 15, q = lane >> 4;
  f32x4 acc[3][4];
  #pragma unroll
  for (int ot = 0; ot < 3; ++ot)
    #pragma unroll
    for (int ti = 0; ti < 4; ++ti)
      acc[ot][ti] = (f32x4){0.f, 0.f, 0.f, 0.f};

  const unsigned short* pws = pw + (size_t)FB * 512 + lane * 8;
  #pragma unroll 1
  for (int k = 0; k < KS; ++k) {
    bf16x8 A0 = *(const bf16x8*)(pws + (size_t)(k * 3 + 0) * 512);
    bf16x8 A1 = *(const bf16x8*)(pws + (size_t)(k * 3 + 1) * 512);
    bf16x8 A2 = *(const bf16x8*)(pws + (size_t)(k * 3 + 2) * 512);
    int rbase = 24 - PAD + k + wt0 + n;
    #pragma unroll
    for (int ti = 0; ti < 4; ++ti) {
      bf16x8 Bf = *(const bf16x8*)(xs + (rbase + ti * 16) * RSTRIDE + q * 8);
      acc[0][ti] = __builtin_amdgcn_mfma_f32_16x16x32_bf16(A0, Bf, acc[0][ti], 0, 0, 0);
      acc[1][ti] = __builtin_amdgcn_mfma_f32_16x16x32_bf16(A1, Bf, acc[1][ti], 0, 0, 0);
      acc[2][ti] = __builtin_amdgcn_mfma_f32_16x16x32_bf16(A2, Bf, acc[2][ti], 0, 0, 0);
    }
  }
  #pragma unroll
  for (int ot = 0; ot < 3; ++ot) {
    int obase = ot * 16 + q * 4;
    if (obase < OC) {
      float Av0 = Aff[SBASE + obase + 0], Bv0 = Bff[SBASE + obase + 0];
      float Av1 = Aff[SBASE + obase + 1], Bv1 = Bff[SBASE + obase + 1];
      float Av2 = Aff[SBASE + obase + 2], Bv2 = Bff[SBASE + obase + 2];
      float Av3 = Aff[SBASE + obase + 3], Bv3 = Bff[SBASE + obase + 3];
      #pragma unroll
      for (int ti = 0; ti < 4; ++ti) {
        int tt = t0 + wt0 + ti * 16 + n;
        if (tt < T) {
          uint2 pk;
          pk.x = pack2bf(fast_elu(fmaf(acc[ot][ti][0], Av0, Bv0)),
                         fast_elu(fmaf(acc[ot][ti][1], Av1, Bv1)));
          pk.y = pack2bf(fast_elu(fmaf(acc[ot][ti][2], Av2, Bv2)),
                         fast_elu(fmaf(acc[ot][ti][3], Av3, Bv3)));
          *reinterpret_cast<uint2*>(feats + (size_t)(b * T + tt) * FC + SBASE + obase) = pk;
        }
      }
    }
  }
}

__device__ void phase3_unit(const MegaArgs& args, int u, int tid, Smem& sm) {
  if (u >= B) {
    int cx = u - B;
    int b = cx / 20, t0 = (cx - b * 20) * TCH;
    for (int idx = tid; idx < CIN * CROWS; idx += 256) {
      int h = idx / CROWS, tl = idx - h * CROWS;
      int gt = t0 - 24 + tl;
      float v = (gt >= 0 && gt < T) ? args.x[(size_t)(b * CIN + h) * T + gt] : 0.f;
      sm.xs[tl * RSTRIDE + h] = f2bf(v);
    }
    for (int idx = tid; idx < 10 * CROWS; idx += 256) {
      int c = idx / CROWS, tl = idx - c * CROWS;
      sm.xs[tl * RSTRIDE + 22 + c] = 0;
    }
    __syncthreads();
    int wv = tid >> 6, lane = tid & 63;
    int wt0 = wv * 64;
    scale_body<9, 0, 0>(sm.xs, args.pw, args.A, args.Bc, args.feats, b, t0, wt0, lane);
    scale_body<25, 27, 40>(sm.xs, args.pw, args.A, args.Bc, args.feats, b, t0, wt0, lane);
    scale_body<49, 102, 80>(sm.xs, args.pw, args.A, args.Bc, args.feats, b, t0, wt0, lane);
    __syncthreads();
  } else {
    int b = u;
    for (int i = tid; i < CIN * NFR; i += 256) sm.a.cl[i] = args.comb[b * CIN * NFR + i];
    __syncthreads();
    int t = tid;
    if (t < NFR) {
      float z = args.ab2[0];
      for (int o = 0; o < 11; ++o) {
        float s = args.ab1[o];
        for (int i = 0; i < CIN; ++i) {
          const float* wr = args.aw1 + o * 66 + i * 3;
          const float* crow = sm.a.cl + i * NFR;
          if (t > 0)       s = fmaf(wr[0], crow[t - 1], s);
          s = fmaf(wr[1], crow[t], s);
          if (t < NFR - 1) s = fmaf(wr[2], crow[t + 1], s);
        }
        float rs = 1.0f / sqrtf(args.av[o] + 1e-5f);
        float y = (s - args.am[o]) * rs * args.ag[o] + args.abt[o];
        y = fmaxf(y, 0.f);
        z = fmaf(args.aw2[o], y, z);
      }
      sm.a.actL[t] = 1.f / (1.f + expf(-z));
    }
    __syncthreads();
    if (t < P) {
      float ai = 0.5f * (sm.a.actL[2 * t] + sm.a.actL[2 * t + 1]);
      sm.a.aiL[t] = ai;
      args.out_acti[b * P + t] = ai;
      sm.a.fL[t] = 1.f / (ai + 1e-6f);
    }
    __syncthreads();
    if (t < 64) {
      float v = sm.a.fL[t] + ((t + 64 < P) ? sm.a.fL[t + 64] : 0.f);
      v = wave_sum_f(v);
      if (t == 0) sm.a.red = v;
    }
    __syncthreads();
    float sw = sm.a.red;
    if (t < P) {
      float ggv = (sm.a.fL[t] / sw) * 5000.f;
      ggv = fminf(fmaxf(ggv, 10.f), 100.f);
      sm.a.fL[t] = ggv;
    }
    __syncthreads();
    if (t < 64) {
      float v = sm.a.fL[t] + ((t + 64 < P) ? sm.a.fL[t + 64] : 0.f);
      v = wave_sum_f(v);
      if (t == 0) sm.a.red = v;
    }
    __syncthreads();
    float r = 5000.f / sm.a.red;
    if (t < P) sm.a.giL[t] = (int)rintf(sm.a.fL[t] * r);
    __syncthreads();
    if (t < 64) {
      int v = sm.a.giL[t] + ((t + 64 < P) ? sm.a.giL[t + 64] : 0);
      v = wave_sum_i(v);
      if (t == 0) sm.a.red = __int_as_float(v);
    }
    __syncthreads();
    if (t == P - 1) sm.a.giL[P - 1] += 5000 - __float_as_int(sm.a.red);
    __syncthreads();
    if (t < P) sm.a.giL[t] = min(max(sm.a.giL[t], 10), 100);
    __syncthreads();
    if (t < 64) {
      int v = sm.a.giL[t] + ((t + 64 < P) ? sm.a.giL[t + 64] : 0);
      v = wave_sum_i(v);
      if (t == 0) sm.a.red = __int_as_float(v);
    }
    __syncthreads();
    if (t == P - 1) sm.a.giL[P - 1] += 5000 - __float_as_int(sm.a.red);
    __syncthreads();
    if (t < P) sm.a.sI[t] = max(sm.a.giL[t], 10);
    __syncthreads();
    #pragma unroll
    for (int off = 1; off < P; off <<= 1) {
      int v = 0;
      if (t < P && t >= off) v = sm.a.sI[t - off];
      __syncthreads();
      if (t < P) sm.a.sI[t] += v;
      __syncthreads();
    }
    if (t < P) {
      int g2 = max(sm.a.giL[t], 10);
      args.out_grid[b * P + t] = (float)g2;
      args.grid_i[b * P + t] = g2;
      args.ends_i[b * P + t] = sm.a.sI[t];
    }
    __syncthreads();
  }
}

// ---------------- Phase 4 unit: ragged avg+max pool + projection ----------------
__device__ void phase4_unit(const MegaArgs& args, int bp, int tid, Smem& sm) {
  int b = bp / P;
  int end = args.ends_i[bp];
  int gr = args.grid_i[bp];
  int start = end - gr;
  bool valid = (end <= T);
  int g = tid % 15;
  int r = tid / 15;
  if (valid && r < 16) {
    float s[8], m[8];
    #pragma unroll
    for (int j = 0; j < 8; ++j) { s[j] = 0.f; m[j] = -INFINITY; }
    const unsigned short* base = args.feats + (size_t)(b * T + start) * FC + g * 8;
    for (int i = r; i < gr; i += 16) {
      uint4 u4 = *reinterpret_cast<const uint4*>(base + (size_t)i * FC);
      unsigned w[4] = {u4.x, u4.y, u4.z, u4.w};
      #pragma unroll
      for (int j = 0; j < 4; ++j) {
        float v0 = bf2f((unsigned short)(w[j] & 0xffffu));
        float v1 = bf2f((unsigned short)(w[j] >> 16));
        s[2 * j] += v0; s[2 * j + 1] += v1;
        m[2 * j] = fmaxf(m[2 * j], v0); m[2 * j + 1] = fmaxf(m[2 * j + 1], v1);
      }
    }
    #pragma unroll
    for (int j = 0; j < 8; ++j) {
      sm.p.s[r * FC + g * 8 + j] = s[j];
      sm.p.m[r * FC + g * 8 + j] = m[j];
    }
  }
  __syncthreads();
  if (tid < FC) {
    if (valid) {
      float s = 0.f, mx = -INFINITY;
      #pragma unroll
      for (int rr = 0; rr < 16; ++rr) {
        s += sm.p.s[rr * FC + tid];
        mx = fmaxf(mx, sm.p.m[rr * FC + tid]);
      }
      sm.p.pooled[tid] = s / (float)gr + mx;
    } else {
      sm.p.pooled[tid] = 0.f;
    }
  }
  __syncthreads();
  if (tid < EMB) {
    float e = args.proj_b[tid];
    const float* wr = args.proj_w + tid * FC;
    #pragma unroll 8
    for (int c = 0; c < FC; ++c) e = fmaf(wr[c], sm.p.pooled[c], e);
    args.out_emb[(size_t)bp * EMB + tid] = e;
  }
  __syncthreads();
}

// ---------------- Mega (cooperative) ----------------
__global__ __launch_bounds__(256) void mega(MegaArgs args) {
  cg::grid_group gg = cg::this_grid();
  __shared__ Smem sm;
  int bid = blockIdx.x;
  int tid = threadIdx.x;
  int stride = gridDim.x;
  for (int u = bid; u < 505; u += stride) phase1_unit(args, u, tid);
  __threadfence();
  gg.sync();
  for (int bc = bid; bc < B * CIN; bc += stride) phase2_unit(args, bc, tid, sm.xsh);
  __threadfence();
  gg.sync();
  for (int u = bid; u < B + 20 * B; u += stride) phase3_unit(args, u, tid, sm);
  __threadfence();
  gg.sync();
  for (int bp = bid; bp < B * P; bp += stride) phase4_unit(args, bp, tid, sm);
}

// ---------------- Fallback wrappers ----------------
__global__ __launch_bounds__(256) void k_phase1(MegaArgs args) {
  phase1_unit(args, blockIdx.x, threadIdx.x);
}
__global__ __launch_bounds__(256) void k_phase2(MegaArgs args) {
  __shared__ Smem sm;
  phase2_unit(args, blockIdx.x, threadIdx.x, sm.xsh);
}
__global__ __launch_bounds__(256) void k_phase3(MegaArgs args) {
  __shared__ Smem sm;
  phase3_unit(args, blockIdx.x, threadIdx.x, sm);
}
__global__ __launch_bounds__(256) void k_phase4(MegaArgs args) {
  __shared__ Smem sm;
  phase4_unit(args, blockIdx.x, threadIdx.x, sm);
}

extern "C" void kernel_launch(void* const* d_in, const int* in_sizes, int n_in,
                              void* d_out, int out_size, void* d_ws, size_t ws_size,
                              hipStream_t stream) {
  float* wsf = (float*)d_ws;
  float* A    = wsf;                 // 120
  float* Bc   = wsf + 120;           // 120
  float* tw   = wsf + 240;           // 3072
  float* comb = wsf + 4096;          // 140800
  int* ends_i = (int*)(wsf + 144896);
  int* grid_i = (int*)(wsf + 148096);
  unsigned short* pw = (unsigned short*)(wsf + 151296);     // 127488 ushorts
  unsigned short* feats = (unsigned short*)(wsf + 215040);  // 19.2M ushorts

  float* out = (float*)d_out;

  static MegaArgs ma;
  for (int s = 0; s < 3; ++s) {
    ma.w1[s] = (const float*)d_in[1 + 8 * s];
    ma.b1[s] = (const float*)d_in[2 + 8 * s];
    ma.w2[s] = (const float*)d_in[3 + 8 * s];
    ma.b2[s] = (const float*)d_in[4 + 8 * s];
    ma.g[s]  = (const float*)d_in[5 + 8 * s];
    ma.bt[s] = (const float*)d_in[6 + 8 * s];
    ma.m[s]  = (const float*)d_in[7 + 8 * s];
    ma.v[s]  = (const float*)d_in[8 + 8 * s];
  }
  ma.x = (const float*)d_in[0];
  ma.pw = pw; ma.A = A; ma.Bc = Bc; ma.tw = tw; ma.comb = comb;
  ma.aw1 = (const float*)d_in[25];
  ma.ab1 = (const float*)d_in[26];
  ma.ag  = (const float*)d_in[27];
  ma.abt = (const float*)d_in[28];
  ma.am  = (const float*)d_in[29];
  ma.av  = (const float*)d_in[30];
  ma.aw2 = (const float*)d_in[31];
  ma.ab2 = (const float*)d_in[32];
  ma.proj_w = (const float*)d_in[33];
  ma.proj_b = (const float*)d_in[34];
  ma.feats = feats;
  ma.out_emb  = out;
  ma.out_grid = out + 204800;
  ma.out_acti = out + 208000;
  ma.ends_i = ends_i; ma.grid_i = grid_i;

  hipError_t err = hipErrorUnknown;
  int dev = 0;
  hipGetDevice(&dev);
  hipDeviceProp_t prop;
  if (hipGetDeviceProperties(&prop, dev) == hipSuccess && prop.cooperativeLaunch) {
    void* ka[1] = {&ma};
    err = hipLaunchCooperativeKernel((const void*)mega, dim3(GRID), dim3(256), ka, 0, stream);
  }
  if (err != hipSuccess) {
    (void)hipGetLastError();  // clear sticky error
    k_phase1<<<505, 256, 0, stream>>>(ma);
    k_phase2<<<B * CIN, 256, 0, stream>>>(ma);
    k_phase3<<<B + 20 * B, 256, 0, stream>>>(ma);
    k_phase4<<<B * P, 256, 0, stream>>>(ma);
  }
}

// Round 15
// 260.324 us; speedup vs baseline: 3.0229x; 3.0229x over previous
//
#include <hip/hip_runtime.h>
#include <hip/hip_bf16.h>
#include <hip/hip_fp8.h>
#include <math.h>
#include <string.h>

#define B 32
#define CIN 22
#define T 5000
#define EMB 64
#define P 100
#define HOP 25
#define OC 40
#define FC 120
#define NBIN 11
#define NFR 200

#define TCH 256
#define CROWS 304     // TCH + 24 halo each side
#define RS8 40        // bytes per fp8 xs row (32 channel slots + 8 pad; 10 dwords -> bank-spread)

#define XPAD 5128
#define TWROW 24

typedef __attribute__((ext_vector_type(4))) float f32x4;

__device__ __forceinline__ unsigned short f2bf(float f) {
  unsigned u = __float_as_uint(f);
  unsigned r = (u + 0x7FFFu + ((u >> 16) & 1u)) >> 16;
  return (unsigned short)r;
}
__device__ __forceinline__ float bf2f(unsigned short u) {
  return __uint_as_float(((unsigned)u) << 16);
}
__device__ __forceinline__ unsigned char f2fp8(float f) {
  __hip_fp8_e4m3 q(f);
  return (unsigned char)q.__x;
}
__device__ __forceinline__ float fast_elu(float y) {
  return y > 0.f ? y : (__builtin_amdgcn_exp2f(y * 1.44269504088896340736f) - 1.0f);
}
__device__ __forceinline__ unsigned pack2bf(float a, float b) {
  __hip_bfloat162 h = __float22bfloat162_rn(make_float2(a, b));
  unsigned u;
  memcpy(&u, &h, 4);
  return u;
}
__device__ __forceinline__ float wave_sum_f(float v) {
  #pragma unroll
  for (int off = 1; off < 64; off <<= 1) v += __shfl_xor(v, off);
  return v;
}
__device__ __forceinline__ int wave_sum_i(int v) {
  #pragma unroll
  for (int off = 1; off < 64; off <<= 1) v += __shfl_xor(v, off);
  return v;
}

// ---------------- K1: setup = fp8 weight-pack + twiddles + affine ----------------
struct SetupArgs {
  const float* w1[3]; const float* b1[3]; const float* w2[3]; const float* b2[3];
  const float* g[3];  const float* bt[3]; const float* m[3];  const float* v[3];
  unsigned char* pw8;
  float* A; float* Bc; float* tw;   // tw: [128][TWROW]
};

__global__ __launch_bounds__(256) void setup_all(SetupArgs args) {
  int bx = blockIdx.x;
  int tid = threadIdx.x;
  if (bx < 498) {
    // pack fused conv weights into fp8 MFMA A-fragment order (8 bytes/lane)
    int id = bx * 256 + tid;
    int s, KS, fbase, idl;
    if (id < 13824)       { s = 0; KS = 9;  fbase = 0;   idl = id; }
    else if (id < 52224)  { s = 1; KS = 25; fbase = 27;  idl = id - 13824; }
    else                  { s = 2; KS = 49; fbase = 102; idl = id - 52224; }
    int fi = idl >> 9, rem = idl & 511;
    int lane = rem >> 3, j = rem & 7;
    int k = fi / 3, ot = fi - k * 3;
    int m = lane & 15, h = ((lane >> 4) << 3) + j;
    int o = ot * 16 + m;
    float val = 0.f;
    if (h < CIN && o < OC) {
      const float* w1 = args.w1[s];
      const float* w2 = args.w2[s];
      for (int i = 0; i < OC; ++i)
        val = fmaf(w2[(o * OC + i) * CIN + h], w1[i * KS + k], val);
    }
    args.pw8[(size_t)(fbase + fi) * 512 + rem] = f2fp8(val);
  } else if (bx < 504) {
    int id = (bx - 498) * 256 + tid;
    if (id < 1408) {
      int n = id & 127, k = id >> 7;
      const double PI = 3.14159265358979323846;
      double ang = -2.0 * PI * (double)((k + 5) * n) / 128.0;
      double win = 0.5 * (1.0 - cos(2.0 * PI * (double)n / 128.0));
      args.tw[n * TWROW + 2 * k]     = (float)(cos(ang) * win);
      args.tw[n * TWROW + 2 * k + 1] = (float)(sin(ang) * win);
    } else if (id < 1536) {
      int n = id - 1408;
      args.tw[n * TWROW + 22] = 0.f;
      args.tw[n * TWROW + 23] = 0.f;
    }
  } else {
    if (tid < 120) {
      int s = tid / 40, o = tid - s * 40;
      const float* w2 = args.w2[s];
      float sc = args.g[s][o] / sqrtf(args.v[s][o] + 1e-5f);
      float cc = args.b2[s][o];
      for (int i = 0; i < OC; ++i) {
        float sh = 0.f;
        for (int h = 0; h < CIN; ++h) sh += w2[(o * OC + i) * CIN + h];
        cc = fmaf(args.b1[s][i], sh, cc);
      }
      args.A[tid] = sc;
      args.Bc[tid] = cc * sc + (args.bt[s][o] - args.m[s][o] * sc);
    }
  }
}

// ---------------- K2: STFT power -> comb (twiddles via wave-uniform global reads) ----------------
__global__ __launch_bounds__(256) void stft_comb(const float* __restrict__ x,
                                                 const float* __restrict__ tw,
                                                 float* __restrict__ comb) {
  __shared__ float xsh[XPAD];
  int bc = blockIdx.x;
  const float* xr = x + (size_t)bc * T;
  int tid = threadIdx.x;
  for (int i = tid; i < XPAD; i += 256) {
    int mm = i - 64;
    mm = (mm < 0) ? -mm : mm;
    mm = (mm >= T) ? (2 * T - 2 - mm) : mm;
    xsh[i] = xr[mm];
  }
  __syncthreads();
  int fr = tid;
  if (fr < NFR) {
    float cr[NBIN], ci[NBIN];
    #pragma unroll
    for (int k = 0; k < NBIN; ++k) { cr[k] = 0.f; ci[k] = 0.f; }
    const float* xw = xsh + fr * HOP;
    #pragma unroll 2
    for (int n = 0; n < 128; ++n) {
      float xv = xw[n];
      const float4* t4 = reinterpret_cast<const float4*>(tw + n * TWROW);
      float4 w0 = t4[0], w1 = t4[1], w2 = t4[2], w3 = t4[3], w4 = t4[4], w5 = t4[5];
      cr[0] = fmaf(xv, w0.x, cr[0]); ci[0] = fmaf(xv, w0.y, ci[0]);
      cr[1] = fmaf(xv, w0.z, cr[1]); ci[1] = fmaf(xv, w0.w, ci[1]);
      cr[2] = fmaf(xv, w1.x, cr[2]); ci[2] = fmaf(xv, w1.y, ci[2]);
      cr[3] = fmaf(xv, w1.z, cr[3]); ci[3] = fmaf(xv, w1.w, ci[3]);
      cr[4] = fmaf(xv, w2.x, cr[4]); ci[4] = fmaf(xv, w2.y, ci[4]);
      cr[5] = fmaf(xv, w2.z, cr[5]); ci[5] = fmaf(xv, w2.w, ci[5]);
      cr[6] = fmaf(xv, w3.x, cr[6]); ci[6] = fmaf(xv, w3.y, ci[6]);
      cr[7] = fmaf(xv, w3.z, cr[7]); ci[7] = fmaf(xv, w3.w, ci[7]);
      cr[8] = fmaf(xv, w4.x, cr[8]); ci[8] = fmaf(xv, w4.y, ci[8]);
      cr[9] = fmaf(xv, w4.z, cr[9]); ci[9] = fmaf(xv, w4.w, ci[9]);
      cr[10] = fmaf(xv, w5.x, cr[10]); ci[10] = fmaf(xv, w5.y, ci[10]);
    }
    float p[NBIN];
    #pragma unroll
    for (int k = 0; k < NBIN; ++k) p[k] = cr[k] * cr[k] + ci[k] * ci[k];
    float beta = 0.f;
    #pragma unroll
    for (int k = 2; k < NBIN; ++k) beta += p[k];
    comb[bc * NFR + fr] = 0.5f * (p[0] + p[1]) + beta * (1.f / 9.f);
  }
}

// ---------------- K3: mid = act_grid blocks first, then fp8 conv (TCH=256) ----------------
struct MidSmem {
  union {
    struct {
      float cl[CIN * NFR];
      float actL[NFR];
      float aiL[P];
      float fL[P];
      int giL[P];
      int sI[P];
      float red;
    } a;
    unsigned char xs8[CROWS * RS8];   // 12160 B, [t][ch] fp8
  };
};

template <int KS, int FB, int SBASE>
__device__ __forceinline__ void scale_body(const unsigned char* __restrict__ xs8,
                                           const unsigned char* __restrict__ pw8,
                                           const float* __restrict__ Aff,
                                           const float* __restrict__ Bff,
                                           unsigned short* __restrict__ feats,
                                           int b, int t0, int wt0, int lane) {
  constexpr int PAD = (KS - 1) / 2;
  const int n = lane & 15, q = lane >> 4;
  f32x4 acc[3][4];
  #pragma unroll
  for (int ot = 0; ot < 3; ++ot)
    #pragma unroll
    for (int ti = 0; ti < 4; ++ti)
      acc[ot][ti] = (f32x4){0.f, 0.f, 0.f, 0.f};

  const unsigned char* pws = pw8 + (size_t)FB * 512 + lane * 8;
  #pragma unroll 1
  for (int k = 0; k < KS; ++k) {
    long long A0 = *(const long long*)(pws + (size_t)(k * 3 + 0) * 512);
    long long A1 = *(const long long*)(pws + (size_t)(k * 3 + 1) * 512);
    long long A2 = *(const long long*)(pws + (size_t)(k * 3 + 2) * 512);
    int rbase = 24 - PAD + k + wt0 + n;
    #pragma unroll
    for (int ti = 0; ti < 4; ++ti) {
      long long Bf = *(const long long*)(xs8 + (rbase + ti * 16) * RS8 + q * 8);
      acc[0][ti] = __builtin_amdgcn_mfma_f32_16x16x32_fp8_fp8(A0, Bf, acc[0][ti], 0, 0, 0);
      acc[1][ti] = __builtin_amdgcn_mfma_f32_16x16x32_fp8_fp8(A1, Bf, acc[1][ti], 0, 0, 0);
      acc[2][ti] = __builtin_amdgcn_mfma_f32_16x16x32_fp8_fp8(A2, Bf, acc[2][ti], 0, 0, 0);
    }
  }
  #pragma unroll
  for (int ot = 0; ot < 3; ++ot) {
    int obase = ot * 16 + q * 4;
    if (obase < OC) {
      float Av0 = Aff[SBASE + obase + 0], Bv0 = Bff[SBASE + obase + 0];
      float Av1 = Aff[SBASE + obase + 1], Bv1 = Bff[SBASE + obase + 1];
      float Av2 = Aff[SBASE + obase + 2], Bv2 = Bff[SBASE + obase + 2];
      float Av3 = Aff[SBASE + obase + 3], Bv3 = Bff[SBASE + obase + 3];
      #pragma unroll
      for (int ti = 0; ti < 4; ++ti) {
        int tt = t0 + wt0 + ti * 16 + n;
        if (tt < T) {
          uint2 pk;
          pk.x = pack2bf(fast_elu(fmaf(acc[ot][ti][0], Av0, Bv0)),
                         fast_elu(fmaf(acc[ot][ti][1], Av1, Bv1)));
          pk.y = pack2bf(fast_elu(fmaf(acc[ot][ti][2], Av2, Bv2)),
                         fast_elu(fmaf(acc[ot][ti][3], Av3, Bv3)));
          *reinterpret_cast<uint2*>(feats + (size_t)(b * T + tt) * FC + SBASE + obase) = pk;
        }
      }
    }
  }
}

struct MidArgs {
  const float* x;
  const unsigned char* pw8;
  const float* Aff; const float* Bff;
  unsigned short* feats;
  const float* comb;
  const float* aw1; const float* ab1;
  const float* ag;  const float* abt;
  const float* am;  const float* av;
  const float* aw2; const float* ab2;
  float* out_grid; float* out_acti;
  int* ends_i; int* grid_i;
};

__global__ __launch_bounds__(256) void mid_all(MidArgs args) {
  __shared__ MidSmem sm;
  int bx = blockIdx.x;
  int tid = threadIdx.x;
  if (bx >= B) {
    // ---- conv: 20 chunks of 256 t per batch ----
    int cx = bx - B;
    int b = cx / 20, t0 = (cx - b * 20) * TCH;
    for (int i = tid; i < CROWS * RS8 / 4; i += 256)
      reinterpret_cast<unsigned*>(sm.xs8)[i] = 0u;
    __syncthreads();
    for (int idx = tid; idx < CIN * CROWS; idx += 256) {
      int h = idx / CROWS, tl = idx - h * CROWS;
      int gt = t0 - 24 + tl;
      float v = (gt >= 0 && gt < T) ? args.x[(size_t)(b * CIN + h) * T + gt] : 0.f;
      sm.xs8[tl * RS8 + h] = f2fp8(v);
    }
    __syncthreads();
    int wv = tid >> 6, lane = tid & 63;
    int wt0 = wv * 64;
    scale_body<9, 0, 0>(sm.xs8, args.pw8, args.Aff, args.Bff, args.feats, b, t0, wt0, lane);
    scale_body<25, 27, 40>(sm.xs8, args.pw8, args.Aff, args.Bff, args.feats, b, t0, wt0, lane);
    scale_body<49, 102, 80>(sm.xs8, args.pw8, args.Aff, args.Bff, args.feats, b, t0, wt0, lane);
  } else {
    // ---- act_grid (fp32, byte-identical to validated pipeline) ----
    int b = bx;
    for (int i = tid; i < CIN * NFR; i += 256) sm.a.cl[i] = args.comb[b * CIN * NFR + i];
    __syncthreads();
    int t = tid;
    if (t < NFR) {
      float z = args.ab2[0];
      for (int o = 0; o < 11; ++o) {
        float s = args.ab1[o];
        for (int i = 0; i < CIN; ++i) {
          const float* wr = args.aw1 + o * 66 + i * 3;
          const float* crow = sm.a.cl + i * NFR;
          if (t > 0)       s = fmaf(wr[0], crow[t - 1], s);
          s = fmaf(wr[1], crow[t], s);
          if (t < NFR - 1) s = fmaf(wr[2], crow[t + 1], s);
        }
        float rs = 1.0f / sqrtf(args.av[o] + 1e-5f);
        float y = (s - args.am[o]) * rs * args.ag[o] + args.abt[o];
        y = fmaxf(y, 0.f);
        z = fmaf(args.aw2[o], y, z);
      }
      sm.a.actL[t] = 1.f / (1.f + expf(-z));
    }
    __syncthreads();
    if (t < P) {
      float ai = 0.5f * (sm.a.actL[2 * t] + sm.a.actL[2 * t + 1]);
      sm.a.aiL[t] = ai;
      args.out_acti[b * P + t] = ai;
      sm.a.fL[t] = 1.f / (ai + 1e-6f);
    }
    __syncthreads();
    if (t < 64) {
      float v = sm.a.fL[t] + ((t + 64 < P) ? sm.a.fL[t + 64] : 0.f);
      v = wave_sum_f(v);
      if (t == 0) sm.a.red = v;
    }
    __syncthreads();
    float sw = sm.a.red;
    if (t < P) {
      float ggv = (sm.a.fL[t] / sw) * 5000.f;
      ggv = fminf(fmaxf(ggv, 10.f), 100.f);
      sm.a.fL[t] = ggv;
    }
    __syncthreads();
    if (t < 64) {
      float v = sm.a.fL[t] + ((t + 64 < P) ? sm.a.fL[t + 64] : 0.f);
      v = wave_sum_f(v);
      if (t == 0) sm.a.red = v;
    }
    __syncthreads();
    float r = 5000.f / sm.a.red;
    if (t < P) sm.a.giL[t] = (int)rintf(sm.a.fL[t] * r);
    __syncthreads();
    if (t < 64) {
      int v = sm.a.giL[t] + ((t + 64 < P) ? sm.a.giL[t + 64] : 0);
      v = wave_sum_i(v);
      if (t == 0) sm.a.red = __int_as_float(v);
    }
    __syncthreads();
    if (t == P - 1) sm.a.giL[P - 1] += 5000 - __float_as_int(sm.a.red);
    __syncthreads();
    if (t < P) sm.a.giL[t] = min(max(sm.a.giL[t], 10), 100);
    __syncthreads();
    if (t < 64) {
      int v = sm.a.giL[t] + ((t + 64 < P) ? sm.a.giL[t + 64] : 0);
      v = wave_sum_i(v);
      if (t == 0) sm.a.red = __int_as_float(v);
    }
    __syncthreads();
    if (t == P - 1) sm.a.giL[P - 1] += 5000 - __float_as_int(sm.a.red);
    __syncthreads();
    if (t < P) sm.a.sI[t] = max(sm.a.giL[t], 10);
    __syncthreads();
    #pragma unroll
    for (int off = 1; off < P; off <<= 1) {
      int v = 0;
      if (t < P && t >= off) v = sm.a.sI[t - off];
      __syncthreads();
      if (t < P) sm.a.sI[t] += v;
      __syncthreads();
    }
    if (t < P) {
      int g2 = max(sm.a.giL[t], 10);
      args.out_grid[b * P + t] = (float)g2;
      args.grid_i[b * P + t] = g2;
      args.ends_i[b * P + t] = sm.a.sI[t];
    }
  }
}

// ---------------- K4: ragged avg+max pool + projection ----------------
__global__ __launch_bounds__(256) void pool_proj(const unsigned short* __restrict__ feats,
                                                 const int* __restrict__ ends_i,
                                                 const int* __restrict__ grid_i,
                                                 const float* __restrict__ proj_w,
                                                 const float* __restrict__ proj_b,
                                                 float* __restrict__ out_emb) {
  int bp = blockIdx.x;
  int b = bp / P;
  int end = ends_i[bp];
  int gr = grid_i[bp];
  int start = end - gr;
  __shared__ float lds_s[16 * FC];
  __shared__ float lds_m[16 * FC];
  __shared__ float pooled[FC];
  int tid = threadIdx.x;
  bool valid = (end <= T);
  int g = tid % 15;
  int r = tid / 15;
  if (valid && r < 16) {
    float s[8], m[8];
    #pragma unroll
    for (int j = 0; j < 8; ++j) { s[j] = 0.f; m[j] = -INFINITY; }
    const unsigned short* base = feats + (size_t)(b * T + start) * FC + g * 8;
    for (int i = r; i < gr; i += 16) {
      uint4 u4 = *reinterpret_cast<const uint4*>(base + (size_t)i * FC);
      unsigned w[4] = {u4.x, u4.y, u4.z, u4.w};
      #pragma unroll
      for (int j = 0; j < 4; ++j) {
        float v0 = bf2f((unsigned short)(w[j] & 0xffffu));
        float v1 = bf2f((unsigned short)(w[j] >> 16));
        s[2 * j] += v0; s[2 * j + 1] += v1;
        m[2 * j] = fmaxf(m[2 * j], v0); m[2 * j + 1] = fmaxf(m[2 * j + 1], v1);
      }
    }
    #pragma unroll
    for (int j = 0; j < 8; ++j) {
      lds_s[r * FC + g * 8 + j] = s[j];
      lds_m[r * FC + g * 8 + j] = m[j];
    }
  }
  __syncthreads();
  if (tid < FC) {
    if (valid) {
      float s = 0.f, mx = -INFINITY;
      #pragma unroll
      for (int rr = 0; rr < 16; ++rr) {
        s += lds_s[rr * FC + tid];
        mx = fmaxf(mx, lds_m[rr * FC + tid]);
      }
      pooled[tid] = s / (float)gr + mx;
    } else {
      pooled[tid] = 0.f;
    }
  }
  __syncthreads();
  if (tid < EMB) {
    float e = proj_b[tid];
    const float* wr = proj_w + tid * FC;
    #pragma unroll 8
    for (int c = 0; c < FC; ++c) e = fmaf(wr[c], pooled[c], e);
    out_emb[(size_t)bp * EMB + tid] = e;
  }
}

extern "C" void kernel_launch(void* const* d_in, const int* in_sizes, int n_in,
                              void* d_out, int out_size, void* d_ws, size_t ws_size,
                              hipStream_t stream) {
  const float* x = (const float*)d_in[0];
  const float* aw1 = (const float*)d_in[25];
  const float* ab1 = (const float*)d_in[26];
  const float* ag  = (const float*)d_in[27];
  const float* abt = (const float*)d_in[28];
  const float* am  = (const float*)d_in[29];
  const float* av  = (const float*)d_in[30];
  const float* aw2 = (const float*)d_in[31];
  const float* ab2 = (const float*)d_in[32];
  const float* proj_w = (const float*)d_in[33];
  const float* proj_b = (const float*)d_in[34];

  float* wsf = (float*)d_ws;
  float* A    = wsf;                 // 120
  float* Bc   = wsf + 120;           // 120
  float* tw   = wsf + 240;           // 3072
  float* comb = wsf + 4096;          // 140800
  int* ends_i = (int*)(wsf + 144896);
  int* grid_i = (int*)(wsf + 148096);
  unsigned char* pw8 = (unsigned char*)(wsf + 151296);      // 127488 bytes (8B-aligned)
  unsigned short* feats = (unsigned short*)(wsf + 215040);  // 19.2M ushorts (38.4 MB)

  float* out      = (float*)d_out;
  float* out_emb  = out;
  float* out_grid = out + 204800;
  float* out_acti = out + 208000;

  SetupArgs sa;
  MidArgs ma;
  for (int s = 0; s < 3; ++s) {
    sa.w1[s] = (const float*)d_in[1 + 8 * s];
    sa.b1[s] = (const float*)d_in[2 + 8 * s];
    sa.w2[s] = (const float*)d_in[3 + 8 * s];
    sa.b2[s] = (const float*)d_in[4 + 8 * s];
    sa.g[s]  = (const float*)d_in[5 + 8 * s];
    sa.bt[s] = (const float*)d_in[6 + 8 * s];
    sa.m[s]  = (const float*)d_in[7 + 8 * s];
    sa.v[s]  = (const float*)d_in[8 + 8 * s];
  }
  sa.pw8 = pw8; sa.A = A; sa.Bc = Bc; sa.tw = tw;

  ma.x = x; ma.pw8 = pw8; ma.Aff = A; ma.Bff = Bc; ma.feats = feats;
  ma.comb = comb; ma.aw1 = aw1; ma.ab1 = ab1; ma.ag = ag; ma.abt = abt;
  ma.am = am; ma.av = av; ma.aw2 = aw2; ma.ab2 = ab2;
  ma.out_grid = out_grid; ma.out_acti = out_acti;
  ma.ends_i = ends_i; ma.grid_i = grid_i;

  setup_all<<<505, 256, 0, stream>>>(sa);
  stft_comb<<<B * CIN, 256, 0, stream>>>(x, tw, comb);
  mid_all<<<B + 20 * B, 256, 0, stream>>>(ma);
  pool_proj<<<B * P, 256, 0, stream>>>(feats, ends_i, grid_i, proj_w, proj_b, out_emb);
}